// Round 1
// baseline (136.285 us; speedup 1.0000x reference)
//
#include <hip/hip_runtime.h>
#include <hip/hip_bf16.h>

#define N_ROWS 131072
#define K_MIX  256
#define D_DIM  128
#define LDSB_STRIDE 136   // shorts per B row: 128 + 8 pad (16B-aligned rows, 2-way max on frag reads)

typedef float  f32x4  __attribute__((ext_vector_type(4)));
typedef short  bf16x8 __attribute__((ext_vector_type(8)));

__device__ inline unsigned short f2bf(float f) {
    unsigned int u = __builtin_bit_cast(unsigned int, f);
    u += 0x7fffu + ((u >> 16) & 1u);      // round-to-nearest-even
    return (unsigned short)(u >> 16);
}

__global__ __launch_bounds__(256, 2)
void mixture_kernel(const float* __restrict__ x,
                    const float* __restrict__ mu,
                    const float* __restrict__ prec,
                    float* __restrict__ out)
{
    __shared__ __align__(16) unsigned short sB[K_MIX * LDSB_STRIDE]; // prec*mu in bf16
    __shared__ float sMusq[K_MIX];
    __shared__ float sRed[4];

    const int tid  = threadIdx.x;
    const int lane = tid & 63;
    const int wave = tid >> 6;
    const int low4 = lane & 15;
    const int q    = lane >> 4;

    const float4* mu4   = (const float4*)mu;
    const float4* prec4 = (const float4*)prec;
    const float4* x4    = (const float4*)x;

    // ---------- Prologue: stage bf16(prec*mu) to LDS, compute musq[k] in fp32 ----------
    #pragma unroll 4
    for (int j = 0; j < 32; ++j) {
        int idx = tid + 256 * j;          // float4 index into mu (K*D/4 = 8192)
        int row = idx >> 5;               // mixture component k
        int c4  = idx & 31;               // float4 within row
        float4 mv = mu4[idx];
        float4 pv = prec4[c4];
        float px = mv.x * pv.x, py = mv.y * pv.y, pz = mv.z * pv.z, pw = mv.w * pv.w;
        ushort4 h;
        h.x = f2bf(px); h.y = f2bf(py); h.z = f2bf(pz); h.w = f2bf(pw);
        *(ushort4*)&sB[row * LDSB_STRIDE + c4 * 4] = h;   // 8B store, 8B aligned
        float ps = px * mv.x + py * mv.y + pz * mv.z + pw * mv.w;
        // reduce across the 32-thread group that owns this row
        ps += __shfl_xor(ps, 1);  ps += __shfl_xor(ps, 2);
        ps += __shfl_xor(ps, 4);  ps += __shfl_xor(ps, 8);
        ps += __shfl_xor(ps, 16);
        if ((tid & 31) == 0) sMusq[row] = ps;
    }
    __syncthreads();

    // ---------- Main: per-wave 32 rows x 256 cols, MFMA 16x16x32 bf16, M-block=2 ----------
    const int rowBase = blockIdx.x * 128 + wave * 32;
    const int r0 = rowBase + low4;        // A rows, tile m=0
    const int r1 = r0 + 16;               // A rows, tile m=1

    f32x4 acc[2][16];
    #pragma unroll
    for (int m = 0; m < 2; ++m)
        #pragma unroll
        for (int c = 0; c < 16; ++c)
            acc[m][c] = (f32x4){0.f, 0.f, 0.f, 0.f};

    float xs = 0.f;   // partial sum of prec * x^2 over this lane's loaded elements

    #pragma unroll
    for (int k = 0; k < 4; ++k) {
        const int d4 = k * 8 + q * 2;     // float4 index within a row (0..31)
        float4 xa0 = x4[r0 * 32 + d4];
        float4 xb0 = x4[r0 * 32 + d4 + 1];
        float4 xa1 = x4[r1 * 32 + d4];
        float4 xb1 = x4[r1 * 32 + d4 + 1];
        float4 pa  = prec4[d4];
        float4 pb  = prec4[d4 + 1];

        xs += pa.x*xa0.x*xa0.x + pa.y*xa0.y*xa0.y + pa.z*xa0.z*xa0.z + pa.w*xa0.w*xa0.w;
        xs += pb.x*xb0.x*xb0.x + pb.y*xb0.y*xb0.y + pb.z*xb0.z*xb0.z + pb.w*xb0.w*xb0.w;
        xs += pa.x*xa1.x*xa1.x + pa.y*xa1.y*xa1.y + pa.z*xa1.z*xa1.z + pa.w*xa1.w*xa1.w;
        xs += pb.x*xb1.x*xb1.x + pb.y*xb1.y*xb1.y + pb.z*xb1.z*xb1.z + pb.w*xb1.w*xb1.w;

        bf16x8 a0, a1;
        a0[0] = (short)f2bf(xa0.x); a0[1] = (short)f2bf(xa0.y);
        a0[2] = (short)f2bf(xa0.z); a0[3] = (short)f2bf(xa0.w);
        a0[4] = (short)f2bf(xb0.x); a0[5] = (short)f2bf(xb0.y);
        a0[6] = (short)f2bf(xb0.z); a0[7] = (short)f2bf(xb0.w);
        a1[0] = (short)f2bf(xa1.x); a1[1] = (short)f2bf(xa1.y);
        a1[2] = (short)f2bf(xa1.z); a1[3] = (short)f2bf(xa1.w);
        a1[4] = (short)f2bf(xb1.x); a1[5] = (short)f2bf(xb1.y);
        a1[6] = (short)f2bf(xb1.z); a1[7] = (short)f2bf(xb1.w);

        #pragma unroll
        for (int c = 0; c < 16; ++c) {
            const unsigned short* bp = &sB[(c * 16 + low4) * LDSB_STRIDE + k * 32 + q * 8];
            bf16x8 b = *(const bf16x8*)bp;   // ds_read_b128, 16B aligned
            acc[0][c] = __builtin_amdgcn_mfma_f32_16x16x32_bf16(a0, b, acc[0][c], 0, 0, 0);
            acc[1][c] = __builtin_amdgcn_mfma_f32_16x16x32_bf16(a1, b, acc[1][c], 0, 0, 0);
        }
    }

    // ---------- Epilogue: per-row logsumexp of (cross - 0.5*musq) ----------
    float musq_l[16];
    #pragma unroll
    for (int c = 0; c < 16; ++c) musq_l[c] = 0.5f * sMusq[c * 16 + low4];

    float lsum = 0.f;
    #pragma unroll
    for (int m = 0; m < 2; ++m) {
        #pragma unroll
        for (int i = 0; i < 4; ++i) {
            float vmax = -1e30f;
            #pragma unroll
            for (int c = 0; c < 16; ++c) {
                float v = acc[m][c][i] - musq_l[c];
                vmax = fmaxf(vmax, v);
            }
            vmax = fmaxf(vmax, __shfl_xor(vmax, 1));
            vmax = fmaxf(vmax, __shfl_xor(vmax, 2));
            vmax = fmaxf(vmax, __shfl_xor(vmax, 4));
            vmax = fmaxf(vmax, __shfl_xor(vmax, 8));
            float s = 0.f;
            #pragma unroll
            for (int c = 0; c < 16; ++c) {
                float v = acc[m][c][i] - musq_l[c];
                s += __expf(v - vmax);
            }
            s += __shfl_xor(s, 1); s += __shfl_xor(s, 2);
            s += __shfl_xor(s, 4); s += __shfl_xor(s, 8);
            if (low4 == 0) lsum += vmax + __logf(s);
        }
    }

    // out = sum_n 0.5*xsq_n - sum_n lse_n
    float part = 0.5f * xs - lsum;
    part += __shfl_xor(part, 32); part += __shfl_xor(part, 16);
    part += __shfl_xor(part, 8);  part += __shfl_xor(part, 4);
    part += __shfl_xor(part, 2);  part += __shfl_xor(part, 1);
    if (lane == 0) sRed[wave] = part;
    __syncthreads();
    if (tid == 0) {
        atomicAdd(out, sRed[0] + sRed[1] + sRed[2] + sRed[3]);
    }
}

extern "C" void kernel_launch(void* const* d_in, const int* in_sizes, int n_in,
                              void* d_out, int out_size, void* d_ws, size_t ws_size,
                              hipStream_t stream) {
    const float* x    = (const float*)d_in[0];
    const float* mu   = (const float*)d_in[1];
    const float* prec = (const float*)d_in[2];
    float* out = (float*)d_out;
    hipMemsetAsync(d_out, 0, sizeof(float), stream);
    mixture_kernel<<<N_ROWS / 128, 256, 0, stream>>>(x, mu, prec, out);
}